// Round 21
// baseline (2008.871 us; speedup 1.0000x reference)
//
#include <hip/hip_runtime.h>
#include <hip/hip_bf16.h>

typedef unsigned short u16;
typedef __attribute__((ext_vector_type(8))) short bf16x8;
typedef __attribute__((ext_vector_type(4))) float f32x4;
typedef __attribute__((ext_vector_type(8))) unsigned short u16x8;
typedef __attribute__((ext_vector_type(4))) unsigned short u16x4;

__device__ __forceinline__ u16 f2bf(float v) {
    __hip_bfloat16 b = __float2bfloat16(v);
    return *reinterpret_cast<u16*>(&b);
}
__device__ __forceinline__ float bf2f(u16 u) {
    __hip_bfloat16 b;
    *reinterpret_cast<u16*>(&b) = u;
    return __bfloat162float(b);
}

// async global->LDS, 16B per lane: lds dest = wave base + lane*16
__device__ __forceinline__ void gl_lds16(const u16* g, u16* l) {
    __builtin_amdgcn_global_load_lds(
        (const __attribute__((address_space(1))) void*)g,
        (__attribute__((address_space(3))) void*)l, 16, 0, 0);
}

// ---------------------------------------------------------------------------
// weight packs -- CS-MAJOR k-order: step t -> cs = t/KK, p = t%KK.
// CT32 plain: col c (t=c>>5, j=c&31) = w[oc][ic=cs*32+j][p]
__global__ void repack_w32(const float* __restrict__ w, u16* __restrict__ wh,
                           int Cout, int Cin, int KK) {
    int i = blockIdx.x * blockDim.x + threadIdx.x;
    int tot = Cout * Cin * KK;
    if (i >= tot) return;
    int oc = i / (Cin * KK);
    int c = i - oc * (Cin * KK);
    int t = c >> 5, j = c & 31;
    int cs = t / KK, p = t - cs * KK;
    int ic = cs * 32 + j;
    wh[i] = f2bf(w[((size_t)oc * Cin + ic) * KK + p]);
}
// CT32 split pack: cols per step t: [hi(32) | lo(32)], cs-major step order
__global__ void repack_split2(const float* __restrict__ w, u16* __restrict__ Ap,
                              int Cout, int CinR, int CinP, int KK, int Ksteps) {
    int cols = Ksteps * 64;
    int idx = blockIdx.x * blockDim.x + threadIdx.x;
    int tot = Cout * cols;
    if (idx >= tot) return;
    int oc = idx / cols, c = idx - oc * cols;
    int t = c >> 6, r = c & 63, half = r >> 5, j = r & 31;
    int cs = t / KK, p = t - cs * KK;
    int ic = cs * 32 + j;
    float v = (p < KK && ic < CinR) ? w[((size_t)oc * CinR + ic) * KK + p] : 0.f;
    u16 h = f2bf(v);
    Ap[idx] = half ? f2bf(v - bf2f(h)) : h;
}
// CT4 split row-window pack: step t = ky; 32 elems = 8 pix x 4 ch; [hi|lo]
__global__ void repack_g4_2(const float* __restrict__ w, u16* __restrict__ Ap,
                            int Cout, int CinR, int KS, int Ksteps) {
    int cols = Ksteps * 64;
    int idx = blockIdx.x * blockDim.x + threadIdx.x;
    int tot = Cout * cols;
    if (idx >= tot) return;
    int oc = idx / cols, c = idx - oc * cols;
    int t = c >> 6, r = c & 63, half = r >> 5, j = r & 31;
    int pix = j >> 2, ch = j & 3;
    float v = (pix < KS && ch < CinR)
                  ? w[(((size_t)oc * CinR + ch) * KS + t) * KS + pix] : 0.f;
    u16 h = f2bf(v);
    Ap[idx] = half ? f2bf(v - bf2f(h)) : h;
}
// CT4 plain row-window pack (bw1): cols [ky][pix(8)][c(4)]
__global__ void repack_g4(const float* __restrict__ w, u16* __restrict__ Ap,
                          int Cout, int CinR, int KS, int Kpp) {
    int idx = blockIdx.x * blockDim.x + threadIdx.x;
    int tot = Cout * Kpp;
    if (idx >= tot) return;
    int oc = idx / Kpp, kk = idx - oc * Kpp;
    int ky = kk >> 5, r = kk & 31;
    int pix = r >> 2, ch = r & 3;
    float v = (pix < KS && ch < CinR)
                  ? w[(((size_t)oc * CinR + ch) * KS + ky) * KS + pix] : 0.f;
    Ap[idx] = f2bf(v);
}

// ---------------------------------------------------------------------------
// extract person m -> padded NHWC-C4 bf16 (Hp=228,Wp=232,halo 2)
__global__ void extract_person4(const float* __restrict__ x,
                                u16* __restrict__ X4, int m, int total) {
    int idx = blockIdx.x * blockDim.x + threadIdx.x;
    if (idx >= total) return;
    int n = idx / 50176;
    int p = idx - n * 50176;
    int y = p / 224, xx = p - y * 224;
    u16 h[4];
    h[3] = 0;
#pragma unroll
    for (int c = 0; c < 3; ++c)
        h[c] = f2bf(x[(((size_t)(n * 3 + c)) * 50176 + p) * 2 + m]);
    size_t o = (((size_t)n * 228 + y + 2) * 232 + xx + 2) * 4;
    *reinterpret_cast<u16x4*>(&X4[o]) = *reinterpret_cast<u16x4*>(h);
}

__global__ void zero_u16(u16* __restrict__ b, size_t n8) {
    size_t i = (size_t)blockIdx.x * blockDim.x + threadIdx.x;
    if (i >= n8) return;
    u16x8 z = {0, 0, 0, 0, 0, 0, 0, 0};
    *reinterpret_cast<u16x8*>(&b[i * 8]) = z;
}
__global__ void zero_halo(u16* __restrict__ buf, int Nn, int Hp, int Wp, int C,
                          int P, int H, int W) {
    int idx = blockIdx.x * blockDim.x + threadIdx.x;
    int tot = Nn * Hp * Wp;
    if (idx >= tot) return;
    int x = idx % Wp, t = idx / Wp, y = t % Hp;
    if (y >= P && y < P + H && x >= P && x < P + W) return;
    u16* p = buf + (size_t)idx * C;
    u16x8 z = {0, 0, 0, 0, 0, 0, 0, 0};
    for (int c = 0; c < C; c += 8) *reinterpret_cast<u16x8*>(&p[c]) = z;
}
// C=4-safe halo zero (u16x4 per pixel)
__global__ void zero_halo_c4(u16* __restrict__ buf, int Nn, int Hp, int Wp,
                             int P, int H, int W) {
    int idx = blockIdx.x * blockDim.x + threadIdx.x;
    int tot = Nn * Hp * Wp;
    if (idx >= tot) return;
    int x = idx % Wp, t = idx / Wp, y = t % Hp;
    if (y >= P && y < P + H && x >= P && x < P + W) return;
    u16x4 z = {0, 0, 0, 0};
    *reinterpret_cast<u16x4*>(&buf[(size_t)idx * 4]) = z;
}

// ---------------------------------------------------------------------------
// unified GEMM-conv (m97-structure), BN=128, BK=32, global_load_lds staging,
// double-buffered, XOR-swizzled 16B slots. bn-MAJOR block order. BM=64 for
// conv2; backbone BM=128. A always LDS-staged (R18: A-direct regressed 3x).
// CT=32: CS-MAJOR k-order (R20). PAR (R21): B stored as 4 stride-2 parity
// planes [py][px][n][58][58][128]; fixed (ky,kx) reads ONE plane at stride-1
// coords -> staging rows contiguous (~4KB/wave vs 16 scattered 64B lines).
// Hp_i carries plane stride in pixels (Nc*58*58) when PAR.
// SPLIT (2-set): A cols per step = [hi32|lo32] (full-8-slot row-XOR swizzle).
// MOUT: 0 = bf16 padded NHWC, 2 = fp32 NCHW, 3 = raw fp32 partial,
//       4 = bf16 parity-plane NHWC (Hp_o = plane stride in pixels)
// ---------------------------------------------------------------------------
template <int BM, int CT, bool PAR, bool SPLIT, int MOUT>
__global__ __launch_bounds__(256) void gconv(
    const u16* __restrict__ A, const u16* __restrict__ B,
    const float* __restrict__ cbias, const float* __restrict__ gam,
    const float* __restrict__ bet,
    u16* __restrict__ outp, float* __restrict__ outf,
    int Nblk, int NHW, int Ksteps, int KSP,
    int Cin, int Hp_i, int Wp_i, int KS,
    int Wout, int HWout,
    int Cout, int Hp_o, int Wp_o, int P_o) {
    constexpr int WAVES_M = (BM == 128) ? 2 : 1;
    constexpr int WM = BM / WAVES_M;
    constexpr int WN = 128 / (4 / WAVES_M);
    constexpr int FM = WM / 16, FN = WN / 16;
    constexpr int ACOLS = SPLIT ? 64 : 32;
    constexpr int AR = (BM * ACOLS * 2) / 4096;

    __shared__ __align__(16) u16 Asb[2][BM * ACOLS];
    __shared__ __align__(16) u16 Bsb[2][128 * 32];

    const int tid = threadIdx.x;
    const int lane = tid & 63, wv = tid >> 6;

    // bijective XCD chunk swizzle (m204)
    const int nwg = gridDim.x, orig = blockIdx.x;
    const int qq = nwg >> 3, rr = nwg & 7, xcd = orig & 7;
    const int L = (xcd < rr ? xcd * (qq + 1) : rr * (qq + 1) + (xcd - rr) * qq) + (orig >> 3);
    // bn-major decomposition: consecutive L share bn
    const int gmK = nwg / Nblk;        // gm * KSP
    const int gm = gmK / KSP;
    const int bn = L / gmK;
    const int midK = L - bn * gmK;
    const int bm = midK % gm;          // bm fastest
    const int kc = midK / gm;
    const int s0 = bn * 128, oc0 = bm * BM;

    const int nsteps = Ksteps;
    const int Arow = Ksteps * ACOLS;   // total u16 cols per A row

    // A staging sources (pre-swizzled)
    const u16* asrc[AR];
#pragma unroll
    for (int r = 0; r < AR; ++r) {
        int idx = r * 256 + tid;
        if constexpr (SPLIT) {
            // 128B-pitch rows: full-8-slot row-XOR swizzle (2-way max on read)
            int row = idx >> 3, slot = idx & 7;
            int c = slot ^ (row & 7);
            asrc[r] = A + (size_t)(oc0 + row) * Arow + c * 8;
        } else {
            int row = idx >> 2, slot = idx & 3;
            int q = slot ^ ((row >> 1) & 3);
            asrc[r] = A + (size_t)(oc0 + row) * Arow + q * 8;
        }
    }
    // B staging row bases
    long brow[2];
#pragma unroll
    for (int r = 0; r < 2; ++r) {
        int idx = r * 256 + tid;
        int srow = idx >> 2;
        int q = (idx & 3) ^ ((idx >> 3) & 3);
        int s = s0 + srow;
        if (s > NHW - 1) s = NHW - 1;
        int n = s / HWout, pos = s - n * HWout;
        int oy = pos / Wout, ox = pos - oy * Wout;
        if constexpr (PAR)
            brow[r] = ((long)(n * 58 + oy) * 58 + ox) * Cin + q * 8;
        else
            brow[r] = (((long)n * Hp_i + 2 * oy) * Wp_i + 2 * ox) * Cin + q * 8;
    }

    auto stage = [&](int buf, int t) {
        long ao = (long)t * ACOLS;
#pragma unroll
        for (int r = 0; r < AR; ++r)
            gl_lds16(asrc[r] + ao, &Asb[buf][(r * 256 + wv * 64) * 8]);
        long so;
        if constexpr (CT == 32) {
            int KK2 = KS * KS;
            int cs = t / KK2, p = t - cs * KK2;   // cs-major
            int ky = p / KS, kx = p - ky * KS;
            if constexpr (PAR) {
                // parity plane ((ky&1),(kx&1)); half-coords (ky>>1,kx>>1)
                so = (long)((ky & 1) * 2 + (kx & 1)) * Hp_i * Cin +
                     ((long)(ky >> 1) * 58 + (kx >> 1)) * Cin + cs * 32;
            } else {
                so = (long)(ky * Wp_i + kx) * Cin + cs * 32;
            }
        } else {
            so = (long)t * Wp_i * 4;
        }
#pragma unroll
        for (int r = 0; r < 2; ++r)
            gl_lds16(B + brow[r] + so, &Bsb[buf][(r * 256 + wv * 64) * 8]);
    };

    const int cl = lane & 15, oct = lane >> 4;
    const int octx = oct ^ ((cl >> 1) & 3);   // B reads (32-u16 pitch)
    const int aslot = oct ^ (cl & 7);         // SPLIT A reads (64-u16 pitch)
    const int wm0 = (WAVES_M == 2) ? (wv & 1) * WM : 0;
    const int wn0 = (WAVES_M == 2) ? (wv >> 1) * WN : wv * WN;

    f32x4 acc[FM][FN] = {};

    const int cs_steps = nsteps / KSP;
    const int t0 = kc * cs_steps, t1 = t0 + cs_steps;

    stage(0, t0);
    __syncthreads();
    for (int t = t0; t < t1; ++t) {
        const int cur = (t - t0) & 1;
        if (t + 1 < t1) stage(cur ^ 1, t + 1);
        bf16x8 af[FM], bfr[FN];
#pragma unroll
        for (int mi = 0; mi < FM; ++mi) {
            if constexpr (SPLIT)
                af[mi] = *reinterpret_cast<const bf16x8*>(
                    &Asb[cur][(wm0 + mi * 16 + cl) * ACOLS + aslot * 8]);
            else
                af[mi] = *reinterpret_cast<const bf16x8*>(
                    &Asb[cur][(wm0 + mi * 16 + cl) * ACOLS + octx * 8]);
        }
#pragma unroll
        for (int ni = 0; ni < FN; ++ni)
            bfr[ni] = *reinterpret_cast<const bf16x8*>(
                &Bsb[cur][(wn0 + ni * 16 + cl) * 32 + octx * 8]);
#pragma unroll
        for (int mi = 0; mi < FM; ++mi)
#pragma unroll
            for (int ni = 0; ni < FN; ++ni)
                acc[mi][ni] = __builtin_amdgcn_mfma_f32_16x16x32_bf16(
                    af[mi], bfr[ni], acc[mi][ni], 0, 0, 0);
        if constexpr (SPLIT) {
            bf16x8 al[FM];
#pragma unroll
            for (int mi = 0; mi < FM; ++mi)
                al[mi] = *reinterpret_cast<const bf16x8*>(
                    &Asb[cur][(wm0 + mi * 16 + cl) * ACOLS + (aslot ^ 4) * 8]);
#pragma unroll
            for (int mi = 0; mi < FM; ++mi)
#pragma unroll
                for (int ni = 0; ni < FN; ++ni)
                    acc[mi][ni] = __builtin_amdgcn_mfma_f32_16x16x32_bf16(
                        al[mi], bfr[ni], acc[mi][ni], 0, 0, 0);
        }
        __syncthreads();
    }

    // epilogue: C row = oc0+wm0+mi*16+oct*4+r, col = s0+wn0+ni*16+cl
#pragma unroll
    for (int ni = 0; ni < FN; ++ni) {
        int s = s0 + wn0 + ni * 16 + cl;
        if (s >= NHW) continue;
        int n = s / HWout, pos = s - n * HWout;
        int oy = pos / Wout, ox = pos - oy * Wout;
#pragma unroll
        for (int mi = 0; mi < FM; ++mi) {
            int oc = oc0 + wm0 + mi * 16 + oct * 4;
            if constexpr (MOUT == 3) {
                float* pf = outf + (size_t)kc * ((size_t)NHW * Cout);
#pragma unroll
                for (int r3 = 0; r3 < 4; ++r3)
                    pf[((size_t)n * Cout + oc + r3) * HWout + pos] = acc[mi][ni][r3];
            } else if constexpr (MOUT == 2) {
#pragma unroll
                for (int r3 = 0; r3 < 4; ++r3) {
                    float v = acc[mi][ni][r3];
                    if (cbias) v += cbias[oc + r3];
                    v = fmaf(v, gam[oc + r3], bet[oc + r3]);
                    v = fmaxf(v, 0.f);
                    outf[((size_t)n * Cout + oc + r3) * HWout + pos] = v;
                }
            } else {
                u16 hh[4];
#pragma unroll
                for (int r3 = 0; r3 < 4; ++r3) {
                    float v = acc[mi][ni][r3];
                    if (cbias) v += cbias[oc + r3];
                    v = fmaf(v, gam[oc + r3], bet[oc + r3]);
                    v = fmaxf(v, 0.f);
                    hh[r3] = f2bf(v);
                }
                size_t ob;
                if constexpr (MOUT == 4) {
                    // parity-plane NHWC: padded (oy+2,ox+2) -> plane
                    // ((oy&1),(ox&1)), coords ((oy+2)>>1,(ox+2)>>1);
                    // Hp_o = plane stride (pixels)
                    ob = ((size_t)((oy & 1) * 2 + (ox & 1)) * Hp_o +
                          ((size_t)n * 58 + ((oy + 2) >> 1)) * 58 +
                          ((ox + 2) >> 1)) * Cout + oc;
                } else {
                    ob = (((size_t)n * Hp_o + oy + P_o) * Wp_o + ox + P_o) * Cout + oc;
                }
                *reinterpret_cast<u16x4*>(&outp[ob]) = *reinterpret_cast<u16x4*>(hh);
            }
        }
    }
}

// ---------------------------------------------------------------------------
// split-K reduce: sum chunks + BN + ReLU; domax=1 -> max-accumulate into out
__global__ void ksum_nchw(const float* __restrict__ part, const float* __restrict__ gam,
                          const float* __restrict__ bet, float* __restrict__ out,
                          size_t tot, size_t str, int HWout, int Cout, int KSP,
                          int domax) {
    size_t i = (size_t)blockIdx.x * blockDim.x + threadIdx.x;
    if (i >= tot) return;
    float s = 0.f;
    for (int kc = 0; kc < KSP; ++kc) s += part[kc * str + i];
    int oc = (int)((i / HWout) % Cout);
    float v = fmaxf(fmaf(s, gam[oc], bet[oc]), 0.f);
    out[i] = domax ? fmaxf(out[i], v) : v;
}
__global__ void ksum_nhwc(const float* __restrict__ part, const float* __restrict__ gam,
                          const float* __restrict__ bet, u16* __restrict__ outp,
                          int NHW, int HWout, int Wout, int Cout,
                          int Hp, int Wp, int P, int KSP, size_t str) {
    int ocq = Cout >> 2;
    int idx = blockIdx.x * blockDim.x + threadIdx.x;
    if (idx >= NHW * ocq) return;
    int s = idx / ocq;
    int oc = (idx - s * ocq) * 4;
    int n = s / HWout, pos = s - n * HWout;
    int oy = pos / Wout, ox = pos - oy * Wout;
    u16 hh[4];
#pragma unroll
    for (int j = 0; j < 4; ++j) {
        float v = 0.f;
        for (int kc = 0; kc < KSP; ++kc)
            v += part[kc * str + ((size_t)n * Cout + oc + j) * HWout + pos];
        v = fmaxf(fmaf(v, gam[oc + j], bet[oc + j]), 0.f);
        hh[j] = f2bf(v);
    }
    size_t ob = (((size_t)n * Hp + oy + P) * Wp + ox + P) * Cout + oc;
    *reinterpret_cast<u16x4*>(&outp[ob]) = *reinterpret_cast<u16x4*>(hh);
}

// ---------------------------------------------------------------------------
__global__ void maxpool2(const float* __restrict__ in, float* __restrict__ out,
                         int NC, int H, int W) {
    int Ho = H >> 1, Wo = W >> 1;
    size_t idx = (size_t)blockIdx.x * blockDim.x + threadIdx.x;
    size_t total = (size_t)NC * Ho * Wo;
    if (idx >= total) return;
    int ox = idx % Wo;
    size_t t = idx / Wo;
    int oy = t % Ho;
    int nc = t / Ho;
    const float* p = in + ((size_t)nc * H + oy * 2) * W + ox * 2;
    out[idx] = fmaxf(fmaxf(p[0], p[1]), fmaxf(p[W], p[W + 1]));
}

// K-split linear pass 1: 64 chunks, grid = nchunks*Nn
__global__ __launch_bounds__(256) void lin_part(
    const float* __restrict__ X, const float* __restrict__ W,
    float* __restrict__ partial, int K, int Kc, int Ncols, int Nn) {
    int c = blockIdx.x / Nn;
    int n = blockIdx.x - c * Nn;
    int lane = threadIdx.x & 63, wv = threadIdx.x >> 6;
    const float4* x4 = reinterpret_cast<const float4*>(X + (size_t)n * K + (size_t)c * Kc);
    int K4 = Kc >> 2;
    for (int j = wv; j < Ncols; j += 4) {
        const float4* w4 =
            reinterpret_cast<const float4*>(W + (size_t)j * K + (size_t)c * Kc);
        float s = 0.f;
        for (int k = lane; k < K4; k += 64) {
            float4 a = x4[k], b = w4[k];
            s = fmaf(a.x, b.x, s);
            s = fmaf(a.y, b.y, s);
            s = fmaf(a.z, b.z, s);
            s = fmaf(a.w, b.w, s);
        }
#pragma unroll
        for (int off = 32; off > 0; off >>= 1) s += __shfl_down(s, off, 64);
        if (lane == 0) partial[((size_t)c * Nn + n) * 64 + j] = s;
    }
}

__global__ void lin_reduce(const float* __restrict__ partial,
                           const float* __restrict__ bias, float* __restrict__ out,
                           int Ncols, int Nn, int nchunks) {
    int t = blockIdx.x * blockDim.x + threadIdx.x;
    if (t >= Nn * Ncols) return;
    int n = t / Ncols, j = t - n * Ncols;
    float s = bias[j];
    for (int c = 0; c < nchunks; ++c) s += partial[((size_t)c * Nn + n) * 64 + j];
    out[t] = s;
}

__global__ void make_rot(const float* __restrict__ o6, float* __restrict__ R,
                         float* __restrict__ bv, int Nc) {
    int n = threadIdx.x;
    if (n >= Nc) return;
    const float PI = 3.14159265358979323846f;
    float a0 = o6[n * 6 + 0] * PI, a1 = o6[n * 6 + 1] * PI, a2 = o6[n * 6 + 2] * PI;
    float c0 = cosf(a0), c1 = cosf(a1), c2 = cosf(a2);
    float s0 = sinf(a0), s1 = sinf(a1), s2 = sinf(a2);
    float Rx[9] = {1, 0, 0, 0, c0, s0, 0, -s0, c0};
    float Ry[9] = {c1, 0, -s1, 0, 1, 0, s1, 0, c1};
    float Rz[9] = {c2, s2, 0, -s2, c2, 0, 0, 0, 1};
    float M[9], Rm[9];
#pragma unroll
    for (int i = 0; i < 3; ++i)
#pragma unroll
        for (int j = 0; j < 3; ++j) {
            float acc = 0.f;
#pragma unroll
            for (int k = 0; k < 3; ++k) acc = fmaf(Ry[i * 3 + k], Rz[k * 3 + j], acc);
            M[i * 3 + j] = acc;
        }
#pragma unroll
    for (int i = 0; i < 3; ++i)
#pragma unroll
        for (int j = 0; j < 3; ++j) {
            float acc = 0.f;
#pragma unroll
            for (int k = 0; k < 3; ++k) acc = fmaf(Rx[i * 3 + k], M[k * 3 + j], acc);
            Rm[i * 3 + j] = acc;
        }
    const float MINV = -3.602826f;
    float v0 = MINV - o6[n * 6 + 3];
    float v1 = MINV - o6[n * 6 + 4];
    float v2 = MINV - o6[n * 6 + 5];
#pragma unroll
    for (int i = 0; i < 3; ++i) {
        float sh = Rm[i * 3 + 0] * v0 + Rm[i * 3 + 1] * v1 + Rm[i * 3 + 2] * v2;
        bv[n * 3 + i] = 255.f * (sh - MINV) / 8.812765f;
        R[n * 9 + i * 3 + 0] = Rm[i * 3 + 0];
        R[n * 9 + i * 3 + 1] = Rm[i * 3 + 1];
        R[n * 9 + i * 3 + 2] = Rm[i * 3 + 2];
    }
}

// z = R.x + bias -> padded NHWC-C4 bf16 (Hp=226, Wp=232, halo 1)
__global__ void rot_apply5(const float* __restrict__ xc, const float* __restrict__ R,
                           const float* __restrict__ bv, u16* __restrict__ z,
                           int m, int total) {
    int idx = blockIdx.x * blockDim.x + threadIdx.x;
    if (idx >= total) return;
    int n = idx / 50176;
    int p = idx - n * 50176;
    int y = p / 224, xx = p - y * 224;
    float x0 = xc[(((size_t)(n * 3 + 0)) * 50176 + p) * 2 + m];
    float x1 = xc[(((size_t)(n * 3 + 1)) * 50176 + p) * 2 + m];
    float x2 = xc[(((size_t)(n * 3 + 2)) * 50176 + p) * 2 + m];
    u16 o[4];
#pragma unroll
    for (int i = 0; i < 3; ++i) {
        float v = fmaf(R[n * 9 + i * 3 + 0], x0,
                  fmaf(R[n * 9 + i * 3 + 1], x1,
                  fmaf(R[n * 9 + i * 3 + 2], x2, bv[n * 3 + i])));
        o[i] = f2bf(v);
    }
    o[3] = 0;
    size_t ob = (((size_t)n * 226 + y + 1) * 232 + xx + 1) * 4;
    *reinterpret_cast<u16x4*>(&z[ob]) = *reinterpret_cast<u16x4*>(o);
}

// ---------------------------------------------------------------------------
static inline int nblk(size_t total, int bs) { return (int)((total + bs - 1) / bs); }

extern "C" void kernel_launch(void* const* d_in, const int* in_sizes, int n_in,
                              void* d_out, int out_size, void* d_ws, size_t ws_size,
                              hipStream_t stream) {
    const float* x   = (const float*)d_in[0];
    const float* w1  = (const float*)d_in[1];
    const float* b1  = (const float*)d_in[2];
    const float* g1  = (const float*)d_in[3];
    const float* be1 = (const float*)d_in[4];
    const float* w2  = (const float*)d_in[5];
    const float* b2  = (const float*)d_in[6];
    const float* g2  = (const float*)d_in[7];
    const float* be2 = (const float*)d_in[8];
    const float* fw  = (const float*)d_in[9];
    const float* fb  = (const float*)d_in[10];
    const float* bw[5], *bg[5], *bb[5];
    for (int i = 0; i < 5; ++i) {
        bw[i] = (const float*)d_in[11 + 3 * i];
        bg[i] = (const float*)d_in[12 + 3 * i];
        bb[i] = (const float*)d_in[13 + 3 * i];
    }
    const float* lw = (const float*)d_in[26];
    const float* lb = (const float*)d_in[27];
    float* out = (float*)d_out;

    const int N = 32;
    const int BS = 256;
    const size_t S_Pp = 100352;

    const size_t E_X4 = (size_t)228 * 232 * 4;   // also hosts Z16p (226*232*4)
    const size_t E_B1 = (size_t)4 * 58 * 58 * 128;  // parity planes (same bytes)
    const size_t E_Zb2 = (size_t)114 * 114 * 64;
    const size_t E_Zb3 = (size_t)58 * 58 * 256;
    const size_t E_Zb4 = (size_t)30 * 30 * 512;
    const size_t E_Zb5 = (size_t)16 * 16 * 1024;

    // SLOTC hosts: C2f (f32), Zb2 (u16), bw4/bw5 split-K partials (f32)
    const size_t slotC_B = E_Zb2 * 2;            // 1,663,488 B/sample
    const size_t per_sample_B = E_X4 * 2 + E_B1 * 2 + slotC_B + S_Pp * 4;
    const size_t apack_u16 = (size_t)128 * 320 + (size_t)128 * 6400 + (size_t)64 * 96 +
                             (size_t)256 * 576 + (size_t)512 * 2304 +
                             (size_t)1024 * 4608 + (size_t)2048 * 9216;
    const size_t fixed_B = (size_t)N * S_Pp * 4 + 131072 * 4 + 8192 + apack_u16 * 2 + 4096;

    int Nc = N;
    while (Nc > 1 && (size_t)Nc * per_sample_B + fixed_B > ws_size) Nc >>= 1;

    // ---- carve workspace ----
    char* cur = (char*)d_ws;
    auto alf = [&](size_t n) { float* p = (float*)cur; cur += ((n + 3) & ~(size_t)3) * 4; return p; };
    auto alu = [&](size_t n) { u16* p = (u16*)cur; cur += ((n + 7) & ~(size_t)7) * 2; return p; };

    float* PM = alf((size_t)N * S_Pp);
    float* O6 = alf(256);
    float* Rm = alf(384);
    float* BV = alf(384);
    float* LP = alf(131072);
    u16* Ap1 = alu((size_t)128 * 320);
    u16* Ap2 = alu((size_t)128 * 6400);
    u16* Ab1 = alu((size_t)64 * 96);
    u16* Ab2 = alu((size_t)256 * 576);
    u16* Ab3 = alu((size_t)512 * 2304);
    u16* Ab4 = alu((size_t)1024 * 4608);
    u16* Ab5 = alu((size_t)2048 * 9216);

    u16* X4p   = alu((size_t)Nc * E_X4);
    u16* Z16p  = X4p;                            // time-disjoint alias
    u16* B1p   = alu((size_t)Nc * E_B1);         // parity planes; hosts Zb3/4/5
    u16* Zb3   = B1p;
    u16* Zb4   = Zb3 + (size_t)Nc * E_Zb3;
    u16* Zb5   = Zb4 + (size_t)Nc * E_Zb4;
    u16* SLOTC = alu((size_t)Nc * slotC_B / 2);  // C2f / Zb2 / split-K partials
    float* C2f = (float*)SLOTC;
    u16* Zb2   = SLOTC;
    float* PartF = (float*)SLOTC;
    float* Pp  = alf((size_t)Nc * S_Pp);

    // ---- weight packs (cs-major for CT32) ----
    repack_g4_2<<<nblk((size_t)128 * 320, BS), BS, 0, stream>>>(w1, Ap1, 128, 3, 5, 5);
    repack_split2<<<nblk((size_t)128 * 6400, BS), BS, 0, stream>>>(w2, Ap2, 128, 128, 128, 25, 100);
    repack_g4<<<nblk((size_t)64 * 96, BS), BS, 0, stream>>>(bw[0], Ab1, 64, 3, 3, 96);
    repack_w32<<<nblk((size_t)256 * 576, BS), BS, 0, stream>>>(bw[1], Ab2, 256, 64, 9);
    repack_w32<<<nblk((size_t)512 * 2304, BS), BS, 0, stream>>>(bw[2], Ab3, 512, 256, 9);
    repack_w32<<<nblk((size_t)1024 * 4608, BS), BS, 0, stream>>>(bw[3], Ab4, 1024, 512, 9);
    repack_w32<<<nblk((size_t)2048 * 9216, BS), BS, 0, stream>>>(bw[4], Ab5, 2048, 1024, 9);

    zero_u16<<<nblk((size_t)Nc * E_X4 / 8, BS), BS, 0, stream>>>(X4p, (size_t)Nc * E_X4 / 8);

    const int NHW1 = Nc * 12544;
    const int Nb1 = (NHW1 + 127) / 128;
    const int NHW2 = Nc * 3136;
    const int Nb2 = (NHW2 + 127) / 128;
    const int NHW3 = Nc * 784;
    const int Nb3 = (NHW3 + 127) / 128;
    const int NHW4 = Nc * 196;
    const int Nb4 = (NHW4 + 127) / 128;
    const int NHW5 = Nc * 49;
    const int Nb5 = (NHW5 + 127) / 128;
    const size_t str4 = (size_t)NHW4 * 1024;
    const size_t str5 = (size_t)NHW5 * 2048;
    const int planePix = Nc * 58 * 58;           // parity plane stride (pixels)

    for (int m = 0; m < 2; ++m) {
        for (int c0 = 0; c0 < N; c0 += Nc) {
            const float* xc = x + (size_t)c0 * 150528 * 2;
            int nNP = Nc * 50176;
            // restore X4p halo (scribbled by previous iteration's Z16p use)
            zero_halo_c4<<<nblk((size_t)Nc * 228 * 232, BS), BS, 0, stream>>>(
                X4p, Nc, 228, 232, 2, 224, 224);
            extract_person4<<<nblk(nNP, BS), BS, 0, stream>>>(xc, X4p, m, nNP);

            // B1p parity-plane halos: each 58x58 plane, interior [1,57)
            zero_halo<<<nblk((size_t)Nc * 4 * 58 * 58, BS), BS, 0, stream>>>(
                B1p, Nc * 4, 58, 58, 128, 1, 56, 56);

            // conv1: CT4 gather, 2-set split, BM=128 -> parity-plane NHWC out
            gconv<128, 4, false, true, 4><<<Nb1, 256, 0, stream>>>(
                Ap1, X4p, b1, g1, be1, B1p, nullptr,
                Nb1, NHW1, 5, 1, 4, 228, 232, 5, 112, 12544, 128, planePix, 0, 0);
            // conv2: BM=64, cs-major, PAR staging (stride-1 plane reads)
            gconv<64, 32, true, true, 2><<<2 * Nb2, 256, 0, stream>>>(
                Ap2, B1p, b2, g2, be2, nullptr, C2f,
                Nb2, NHW2, 100, 1, 128, planePix, 58, 5, 56, 3136, 128, 0, 0, 0);
            maxpool2<<<nblk((size_t)Nc * S_Pp, BS), BS, 0, stream>>>(C2f, Pp, Nc * 128, 56, 56);

            lin_part<<<64 * Nc, 256, 0, stream>>>(Pp, fw, LP, 100352, 1568, 6, Nc);
            lin_reduce<<<nblk(Nc * 6, 64), 64, 0, stream>>>(LP, fb, O6, 6, Nc, 64);
            make_rot<<<1, 64, 0, stream>>>(O6, Rm, BV, Nc);
            // Z16p (aliases X4p, conv1 done): zero its halo then write interior
            zero_halo_c4<<<nblk((size_t)Nc * 226 * 232, BS), BS, 0, stream>>>(
                Z16p, Nc, 226, 232, 1, 224, 224);
            rot_apply5<<<nblk(nNP, BS), BS, 0, stream>>>(xc, Rm, BV, Z16p, m, nNP);

            zero_halo<<<nblk((size_t)Nc * 114 * 114, BS), BS, 0, stream>>>(Zb2, Nc, 114, 114, 64, 1, 112, 112);
            zero_halo<<<nblk((size_t)Nc * 58 * 58, BS), BS, 0, stream>>>(Zb3, Nc, 58, 58, 256, 1, 56, 56);
            zero_halo<<<nblk((size_t)Nc * 30 * 30, BS), BS, 0, stream>>>(Zb4, Nc, 30, 30, 512, 1, 28, 28);
            zero_halo<<<nblk((size_t)Nc * 16 * 16, BS), BS, 0, stream>>>(Zb5, Nc, 16, 16, 1024, 1, 14, 14);

            // backbone (R13 tile configs; CT32 cs-major, non-PAR)
            gconv<64, 4, false, false, 0><<<Nb1, 256, 0, stream>>>(
                Ab1, Z16p, nullptr, bg[0], bb[0], Zb2, nullptr,
                Nb1, NHW1, 3, 1, 4, 226, 232, 3, 112, 12544, 64, 114, 114, 1);
            gconv<128, 32, false, false, 0><<<2 * Nb2, 256, 0, stream>>>(
                Ab2, Zb2, nullptr, bg[1], bb[1], Zb3, nullptr,
                Nb2, NHW2, 18, 1, 64, 114, 114, 3, 56, 3136, 256, 58, 58, 1);
            gconv<128, 32, false, false, 0><<<4 * Nb3, 256, 0, stream>>>(
                Ab3, Zb3, nullptr, bg[2], bb[2], Zb4, nullptr,
                Nb3, NHW3, 72, 1, 256, 58, 58, 3, 28, 784, 512, 30, 30, 1);
            // bw4: BM=128, split-K=2 -> reduce -> padded NHWC Zb5
            gconv<128, 32, false, false, 3><<<8 * 2 * Nb4, 256, 0, stream>>>(
                Ab4, Zb4, nullptr, nullptr, nullptr, nullptr, PartF,
                Nb4, NHW4, 144, 2, 512, 30, 30, 3, 14, 196, 1024, 0, 0, 0);
            ksum_nhwc<<<nblk((size_t)NHW4 * 256, BS), BS, 0, stream>>>(
                PartF, bg[3], bb[3], Zb5, NHW4, 196, 14, 1024, 16, 16, 1, 2, str4);
            // bw5: BM=128, split-K=4 -> reduce (+BN+ReLU) -> PMc (max on m=1)
            gconv<128, 32, false, false, 3><<<16 * 4 * Nb5, 256, 0, stream>>>(
                Ab5, Zb5, nullptr, nullptr, nullptr, nullptr, PartF,
                Nb5, NHW5, 288, 4, 1024, 16, 16, 3, 7, 49, 2048, 0, 0, 0);
            float* PMc = PM + (size_t)c0 * S_Pp;
            ksum_nchw<<<nblk((size_t)NHW5 * 2048, BS), BS, 0, stream>>>(
                PartF, bg[4], bb[4], PMc, (size_t)NHW5 * 2048, str5, 49, 2048, 4, m);
        }
    }

    lin_part<<<64 * N, 256, 0, stream>>>(PM, lw, LP, 100352, 1568, 60, N);
    lin_reduce<<<nblk(N * 60, 64), 64, 0, stream>>>(LP, lb, out, 60, N, 64);
}

// Round 22
// 1978.432 us; speedup vs baseline: 1.0154x; 1.0154x over previous
//
#include <hip/hip_runtime.h>
#include <hip/hip_bf16.h>

typedef unsigned short u16;
typedef __attribute__((ext_vector_type(8))) short bf16x8;
typedef __attribute__((ext_vector_type(4))) float f32x4;
typedef __attribute__((ext_vector_type(8))) unsigned short u16x8;
typedef __attribute__((ext_vector_type(4))) unsigned short u16x4;

__device__ __forceinline__ u16 f2bf(float v) {
    __hip_bfloat16 b = __float2bfloat16(v);
    return *reinterpret_cast<u16*>(&b);
}
__device__ __forceinline__ float bf2f(u16 u) {
    __hip_bfloat16 b;
    *reinterpret_cast<u16*>(&b) = u;
    return __bfloat162float(b);
}

// async global->LDS, 16B per lane: lds dest = wave base + lane*16
__device__ __forceinline__ void gl_lds16(const u16* g, u16* l) {
    __builtin_amdgcn_global_load_lds(
        (const __attribute__((address_space(1))) void*)g,
        (__attribute__((address_space(3))) void*)l, 16, 0, 0);
}

// ---------------------------------------------------------------------------
// weight packs
// CT32 plain: OIHW fp32 -> [oc][p*Cin+ic]
__global__ void repack_w32(const float* __restrict__ w, u16* __restrict__ wh,
                           int Cout, int Cin, int KK) {
    int i = blockIdx.x * blockDim.x + threadIdx.x;
    int tot = Cout * Cin * KK;
    if (i >= tot) return;
    int oc = i / (Cin * KK);
    int r = i - oc * (Cin * KK);
    int p = r / Cin, ic = r - p * Cin;
    wh[(size_t)oc * (Cin * KK) + (size_t)p * Cin + ic] =
        f2bf(w[((size_t)oc * Cin + ic) * KK + p]);
}
// CT32 split pack: cols per step t: [hi(32) | lo(32)]
__global__ void repack_split2(const float* __restrict__ w, u16* __restrict__ Ap,
                              int Cout, int CinR, int CinP, int KK, int Ksteps) {
    int cols = Ksteps * 64;
    int idx = blockIdx.x * blockDim.x + threadIdx.x;
    int tot = Cout * cols;
    if (idx >= tot) return;
    int oc = idx / cols, c = idx - oc * cols;
    int t = c >> 6, r = c & 63, half = r >> 5, j = r & 31;
    int kk = t * 32 + j;
    int p = kk / CinP, ic = kk - p * CinP;
    float v = (p < KK && ic < CinR) ? w[((size_t)oc * CinR + ic) * KK + p] : 0.f;
    u16 h = f2bf(v);
    Ap[idx] = half ? f2bf(v - bf2f(h)) : h;
}
// CT4 split row-window pack: step t = ky; 32 elems = 8 pix x 4 ch; [hi|lo]
__global__ void repack_g4_2(const float* __restrict__ w, u16* __restrict__ Ap,
                            int Cout, int CinR, int KS, int Ksteps) {
    int cols = Ksteps * 64;
    int idx = blockIdx.x * blockDim.x + threadIdx.x;
    int tot = Cout * cols;
    if (idx >= tot) return;
    int oc = idx / cols, c = idx - oc * cols;
    int t = c >> 6, r = c & 63, half = r >> 5, j = r & 31;
    int pix = j >> 2, ch = j & 3;
    float v = (pix < KS && ch < CinR)
                  ? w[(((size_t)oc * CinR + ch) * KS + t) * KS + pix] : 0.f;
    u16 h = f2bf(v);
    Ap[idx] = half ? f2bf(v - bf2f(h)) : h;
}
// CT4 plain row-window pack (bw1): cols [ky][pix(8)][c(4)]
__global__ void repack_g4(const float* __restrict__ w, u16* __restrict__ Ap,
                          int Cout, int CinR, int KS, int Kpp) {
    int idx = blockIdx.x * blockDim.x + threadIdx.x;
    int tot = Cout * Kpp;
    if (idx >= tot) return;
    int oc = idx / Kpp, kk = idx - oc * Kpp;
    int ky = kk >> 5, r = kk & 31;
    int pix = r >> 2, ch = r & 3;
    float v = (pix < KS && ch < CinR)
                  ? w[(((size_t)oc * CinR + ch) * KS + ky) * KS + pix] : 0.f;
    Ap[idx] = f2bf(v);
}

// ---------------------------------------------------------------------------
// extract person m -> padded NHWC-C4 bf16 (Hp=228,Wp=232,halo 2)
__global__ void extract_person4(const float* __restrict__ x,
                                u16* __restrict__ X4, int m, int total) {
    int idx = blockIdx.x * blockDim.x + threadIdx.x;
    if (idx >= total) return;
    int n = idx / 50176;
    int p = idx - n * 50176;
    int y = p / 224, xx = p - y * 224;
    u16 h[4];
    h[3] = 0;
#pragma unroll
    for (int c = 0; c < 3; ++c)
        h[c] = f2bf(x[(((size_t)(n * 3 + c)) * 50176 + p) * 2 + m]);
    size_t o = (((size_t)n * 228 + y + 2) * 232 + xx + 2) * 4;
    *reinterpret_cast<u16x4*>(&X4[o]) = *reinterpret_cast<u16x4*>(h);
}

__global__ void zero_u16(u16* __restrict__ b, size_t n8) {
    size_t i = (size_t)blockIdx.x * blockDim.x + threadIdx.x;
    if (i >= n8) return;
    u16x8 z = {0, 0, 0, 0, 0, 0, 0, 0};
    *reinterpret_cast<u16x8*>(&b[i * 8]) = z;
}
__global__ void zero_halo(u16* __restrict__ buf, int Nn, int Hp, int Wp, int C,
                          int P, int H, int W) {
    int idx = blockIdx.x * blockDim.x + threadIdx.x;
    int tot = Nn * Hp * Wp;
    if (idx >= tot) return;
    int x = idx % Wp, t = idx / Wp, y = t % Hp;
    if (y >= P && y < P + H && x >= P && x < P + W) return;
    u16* p = buf + (size_t)idx * C;
    u16x8 z = {0, 0, 0, 0, 0, 0, 0, 0};
    for (int c = 0; c < C; c += 8) *reinterpret_cast<u16x8*>(&p[c]) = z;
}
// C=4-safe halo zero (u16x4 per pixel)
__global__ void zero_halo_c4(u16* __restrict__ buf, int Nn, int Hp, int Wp,
                             int P, int H, int W) {
    int idx = blockIdx.x * blockDim.x + threadIdx.x;
    int tot = Nn * Hp * Wp;
    if (idx >= tot) return;
    int x = idx % Wp, t = idx / Wp, y = t % Hp;
    if (y >= P && y < P + H && x >= P && x < P + W) return;
    u16x4 z = {0, 0, 0, 0};
    *reinterpret_cast<u16x4*>(&buf[(size_t)idx * 4]) = z;
}

// ---------------------------------------------------------------------------
// unified GEMM-conv (m97-structure), BN=128, BK=32, global_load_lds staging,
// double-buffered, XOR-swizzled 16B slots. bn-MAJOR block order (B L2-shared
// across the gm oc-blocks and KSP chunks of one bn tile). BM=64 for conv2
// (R16 win); backbone BM=128. A always LDS-staged (R18: A-direct regressed
// 3x). R20 cs-major cut FETCH 40% but not time; R21 parity planes null ->
// conv2 is at the 2-barrier structure's latency ceiling (~670 TF MFMA-pipe
// incl. 2x split). This is the best-measured configuration (1.980 ms).
// SPLIT (2-set): A cols per step = [hi32|lo32] (full-8-slot row-XOR swizzle,
// 0 conflicts verified R10). Per step: stage Bh once, acc += Ah*Bh + Al*Bh.
// KSP: split-K chunks, MOUT=3 writes raw fp32 partial [kc][NCHW].
// MOUT: 0 = bf16 padded NHWC, 2 = fp32 NCHW, 3 = raw fp32 partial
// ---------------------------------------------------------------------------
template <int BM, int CT, bool SPLIT, int MOUT>
__global__ __launch_bounds__(256) void gconv(
    const u16* __restrict__ A, const u16* __restrict__ B,
    const float* __restrict__ cbias, const float* __restrict__ gam,
    const float* __restrict__ bet,
    u16* __restrict__ outp, float* __restrict__ outf,
    int Nblk, int NHW, int Ksteps, int KSP,
    int Cin, int Hp_i, int Wp_i, int KS,
    int Wout, int HWout,
    int Cout, int Hp_o, int Wp_o, int P_o) {
    constexpr int WAVES_M = (BM == 128) ? 2 : 1;
    constexpr int WM = BM / WAVES_M;
    constexpr int WN = 128 / (4 / WAVES_M);
    constexpr int FM = WM / 16, FN = WN / 16;
    constexpr int ACOLS = SPLIT ? 64 : 32;
    constexpr int AR = (BM * ACOLS * 2) / 4096;

    __shared__ __align__(16) u16 Asb[2][BM * ACOLS];
    __shared__ __align__(16) u16 Bsb[2][128 * 32];

    const int tid = threadIdx.x;
    const int lane = tid & 63, wv = tid >> 6;

    // bijective XCD chunk swizzle (m204)
    const int nwg = gridDim.x, orig = blockIdx.x;
    const int qq = nwg >> 3, rr = nwg & 7, xcd = orig & 7;
    const int L = (xcd < rr ? xcd * (qq + 1) : rr * (qq + 1) + (xcd - rr) * qq) + (orig >> 3);
    // bn-major decomposition: consecutive L share bn
    const int gmK = nwg / Nblk;        // gm * KSP
    const int gm = gmK / KSP;
    const int bn = L / gmK;
    const int midK = L - bn * gmK;
    const int bm = midK % gm;          // bm fastest
    const int kc = midK / gm;
    const int s0 = bn * 128, oc0 = bm * BM;

    const int nsteps = Ksteps;
    const int Arow = Ksteps * ACOLS;   // total u16 cols per A row

    // A staging sources (pre-swizzled)
    const u16* asrc[AR];
#pragma unroll
    for (int r = 0; r < AR; ++r) {
        int idx = r * 256 + tid;
        if constexpr (SPLIT) {
            // 128B-pitch rows: full-8-slot row-XOR swizzle (2-way max on read)
            int row = idx >> 3, slot = idx & 7;
            int c = slot ^ (row & 7);
            asrc[r] = A + (size_t)(oc0 + row) * Arow + c * 8;
        } else {
            int row = idx >> 2, slot = idx & 3;
            int q = slot ^ ((row >> 1) & 3);
            asrc[r] = A + (size_t)(oc0 + row) * Arow + q * 8;
        }
    }
    // B staging row bases (padded NHWC gather; stored pixel base (2oy,2ox))
    long brow[2];
#pragma unroll
    for (int r = 0; r < 2; ++r) {
        int idx = r * 256 + tid;
        int srow = idx >> 2;
        int q = (idx & 3) ^ ((idx >> 3) & 3);
        int s = s0 + srow;
        if (s > NHW - 1) s = NHW - 1;
        int n = s / HWout, pos = s - n * HWout;
        int oy = pos / Wout, ox = pos - oy * Wout;
        brow[r] = (((long)n * Hp_i + 2 * oy) * Wp_i + 2 * ox) * Cin + q * 8;
    }

    auto stage = [&](int buf, int t) {
        long ao = (long)t * ACOLS;
#pragma unroll
        for (int r = 0; r < AR; ++r)
            gl_lds16(asrc[r] + ao, &Asb[buf][(r * 256 + wv * 64) * 8]);
        long so;
        if constexpr (CT == 32) {
            int csn = Cin >> 5;
            int p = t / csn, cs = t - p * csn;
            int ky = p / KS, kx = p - ky * KS;
            so = (long)(ky * Wp_i + kx) * Cin + cs * 32;
        } else {
            so = (long)t * Wp_i * 4;
        }
#pragma unroll
        for (int r = 0; r < 2; ++r)
            gl_lds16(B + brow[r] + so, &Bsb[buf][(r * 256 + wv * 64) * 8]);
    };

    const int cl = lane & 15, oct = lane >> 4;
    const int octx = oct ^ ((cl >> 1) & 3);   // B reads (32-u16 pitch)
    const int aslot = oct ^ (cl & 7);         // SPLIT A reads (64-u16 pitch)
    const int wm0 = (WAVES_M == 2) ? (wv & 1) * WM : 0;
    const int wn0 = (WAVES_M == 2) ? (wv >> 1) * WN : wv * WN;

    f32x4 acc[FM][FN] = {};

    const int cs_steps = nsteps / KSP;
    const int t0 = kc * cs_steps, t1 = t0 + cs_steps;

    stage(0, t0);
    __syncthreads();
    for (int t = t0; t < t1; ++t) {
        const int cur = (t - t0) & 1;
        if (t + 1 < t1) stage(cur ^ 1, t + 1);
        bf16x8 af[FM], bfr[FN];
#pragma unroll
        for (int mi = 0; mi < FM; ++mi) {
            if constexpr (SPLIT)
                af[mi] = *reinterpret_cast<const bf16x8*>(
                    &Asb[cur][(wm0 + mi * 16 + cl) * ACOLS + aslot * 8]);
            else
                af[mi] = *reinterpret_cast<const bf16x8*>(
                    &Asb[cur][(wm0 + mi * 16 + cl) * ACOLS + octx * 8]);
        }
#pragma unroll
        for (int ni = 0; ni < FN; ++ni)
            bfr[ni] = *reinterpret_cast<const bf16x8*>(
                &Bsb[cur][(wn0 + ni * 16 + cl) * 32 + octx * 8]);
#pragma unroll
        for (int mi = 0; mi < FM; ++mi)
#pragma unroll
            for (int ni = 0; ni < FN; ++ni)
                acc[mi][ni] = __builtin_amdgcn_mfma_f32_16x16x32_bf16(
                    af[mi], bfr[ni], acc[mi][ni], 0, 0, 0);
        if constexpr (SPLIT) {
            bf16x8 al[FM];
#pragma unroll
            for (int mi = 0; mi < FM; ++mi)
                al[mi] = *reinterpret_cast<const bf16x8*>(
                    &Asb[cur][(wm0 + mi * 16 + cl) * ACOLS + (aslot ^ 4) * 8]);
#pragma unroll
            for (int mi = 0; mi < FM; ++mi)
#pragma unroll
                for (int ni = 0; ni < FN; ++ni)
                    acc[mi][ni] = __builtin_amdgcn_mfma_f32_16x16x32_bf16(
                        al[mi], bfr[ni], acc[mi][ni], 0, 0, 0);
        }
        __syncthreads();
    }

    // epilogue: C row = oc0+wm0+mi*16+oct*4+r, col = s0+wn0+ni*16+cl
#pragma unroll
    for (int ni = 0; ni < FN; ++ni) {
        int s = s0 + wn0 + ni * 16 + cl;
        if (s >= NHW) continue;
        int n = s / HWout, pos = s - n * HWout;
        int oy = pos / Wout, ox = pos - oy * Wout;
#pragma unroll
        for (int mi = 0; mi < FM; ++mi) {
            int oc = oc0 + wm0 + mi * 16 + oct * 4;
            if constexpr (MOUT == 3) {
                float* pf = outf + (size_t)kc * ((size_t)NHW * Cout);
#pragma unroll
                for (int r3 = 0; r3 < 4; ++r3)
                    pf[((size_t)n * Cout + oc + r3) * HWout + pos] = acc[mi][ni][r3];
            } else if constexpr (MOUT == 2) {
#pragma unroll
                for (int r3 = 0; r3 < 4; ++r3) {
                    float v = acc[mi][ni][r3];
                    if (cbias) v += cbias[oc + r3];
                    v = fmaf(v, gam[oc + r3], bet[oc + r3]);
                    v = fmaxf(v, 0.f);
                    outf[((size_t)n * Cout + oc + r3) * HWout + pos] = v;
                }
            } else {
                u16 hh[4];
#pragma unroll
                for (int r3 = 0; r3 < 4; ++r3) {
                    float v = acc[mi][ni][r3];
                    if (cbias) v += cbias[oc + r3];
                    v = fmaf(v, gam[oc + r3], bet[oc + r3]);
                    v = fmaxf(v, 0.f);
                    hh[r3] = f2bf(v);
                }
                size_t ob = (((size_t)n * Hp_o + oy + P_o) * Wp_o + ox + P_o) * Cout + oc;
                *reinterpret_cast<u16x4*>(&outp[ob]) = *reinterpret_cast<u16x4*>(hh);
            }
        }
    }
}

// ---------------------------------------------------------------------------
// split-K reduce: sum chunks + BN + ReLU; domax=1 -> max-accumulate into out
__global__ void ksum_nchw(const float* __restrict__ part, const float* __restrict__ gam,
                          const float* __restrict__ bet, float* __restrict__ out,
                          size_t tot, size_t str, int HWout, int Cout, int KSP,
                          int domax) {
    size_t i = (size_t)blockIdx.x * blockDim.x + threadIdx.x;
    if (i >= tot) return;
    float s = 0.f;
    for (int kc = 0; kc < KSP; ++kc) s += part[kc * str + i];
    int oc = (int)((i / HWout) % Cout);
    float v = fmaxf(fmaf(s, gam[oc], bet[oc]), 0.f);
    out[i] = domax ? fmaxf(out[i], v) : v;
}
__global__ void ksum_nhwc(const float* __restrict__ part, const float* __restrict__ gam,
                          const float* __restrict__ bet, u16* __restrict__ outp,
                          int NHW, int HWout, int Wout, int Cout,
                          int Hp, int Wp, int P, int KSP, size_t str) {
    int ocq = Cout >> 2;
    int idx = blockIdx.x * blockDim.x + threadIdx.x;
    if (idx >= NHW * ocq) return;
    int s = idx / ocq;
    int oc = (idx - s * ocq) * 4;
    int n = s / HWout, pos = s - n * HWout;
    int oy = pos / Wout, ox = pos - oy * Wout;
    u16 hh[4];
#pragma unroll
    for (int j = 0; j < 4; ++j) {
        float v = 0.f;
        for (int kc = 0; kc < KSP; ++kc)
            v += part[kc * str + ((size_t)n * Cout + oc + j) * HWout + pos];
        v = fmaxf(fmaf(v, gam[oc + j], bet[oc + j]), 0.f);
        hh[j] = f2bf(v);
    }
    size_t ob = (((size_t)n * Hp + oy + P) * Wp + ox + P) * Cout + oc;
    *reinterpret_cast<u16x4*>(&outp[ob]) = *reinterpret_cast<u16x4*>(hh);
}

// ---------------------------------------------------------------------------
__global__ void maxpool2(const float* __restrict__ in, float* __restrict__ out,
                         int NC, int H, int W) {
    int Ho = H >> 1, Wo = W >> 1;
    size_t idx = (size_t)blockIdx.x * blockDim.x + threadIdx.x;
    size_t total = (size_t)NC * Ho * Wo;
    if (idx >= total) return;
    int ox = idx % Wo;
    size_t t = idx / Wo;
    int oy = t % Ho;
    int nc = t / Ho;
    const float* p = in + ((size_t)nc * H + oy * 2) * W + ox * 2;
    out[idx] = fmaxf(fmaxf(p[0], p[1]), fmaxf(p[W], p[W + 1]));
}

// K-split linear pass 1: 64 chunks, grid = nchunks*Nn
__global__ __launch_bounds__(256) void lin_part(
    const float* __restrict__ X, const float* __restrict__ W,
    float* __restrict__ partial, int K, int Kc, int Ncols, int Nn) {
    int c = blockIdx.x / Nn;
    int n = blockIdx.x - c * Nn;
    int lane = threadIdx.x & 63, wv = threadIdx.x >> 6;
    const float4* x4 = reinterpret_cast<const float4*>(X + (size_t)n * K + (size_t)c * Kc);
    int K4 = Kc >> 2;
    for (int j = wv; j < Ncols; j += 4) {
        const float4* w4 =
            reinterpret_cast<const float4*>(W + (size_t)j * K + (size_t)c * Kc);
        float s = 0.f;
        for (int k = lane; k < K4; k += 64) {
            float4 a = x4[k], b = w4[k];
            s = fmaf(a.x, b.x, s);
            s = fmaf(a.y, b.y, s);
            s = fmaf(a.z, b.z, s);
            s = fmaf(a.w, b.w, s);
        }
#pragma unroll
        for (int off = 32; off > 0; off >>= 1) s += __shfl_down(s, off, 64);
        if (lane == 0) partial[((size_t)c * Nn + n) * 64 + j] = s;
    }
}

__global__ void lin_reduce(const float* __restrict__ partial,
                           const float* __restrict__ bias, float* __restrict__ out,
                           int Ncols, int Nn, int nchunks) {
    int t = blockIdx.x * blockDim.x + threadIdx.x;
    if (t >= Nn * Ncols) return;
    int n = t / Ncols, j = t - n * Ncols;
    float s = bias[j];
    for (int c = 0; c < nchunks; ++c) s += partial[((size_t)c * Nn + n) * 64 + j];
    out[t] = s;
}

__global__ void make_rot(const float* __restrict__ o6, float* __restrict__ R,
                         float* __restrict__ bv, int Nc) {
    int n = threadIdx.x;
    if (n >= Nc) return;
    const float PI = 3.14159265358979323846f;
    float a0 = o6[n * 6 + 0] * PI, a1 = o6[n * 6 + 1] * PI, a2 = o6[n * 6 + 2] * PI;
    float c0 = cosf(a0), c1 = cosf(a1), c2 = cosf(a2);
    float s0 = sinf(a0), s1 = sinf(a1), s2 = sinf(a2);
    float Rx[9] = {1, 0, 0, 0, c0, s0, 0, -s0, c0};
    float Ry[9] = {c1, 0, -s1, 0, 1, 0, s1, 0, c1};
    float Rz[9] = {c2, s2, 0, -s2, c2, 0, 0, 0, 1};
    float M[9], Rm[9];
#pragma unroll
    for (int i = 0; i < 3; ++i)
#pragma unroll
        for (int j = 0; j < 3; ++j) {
            float acc = 0.f;
#pragma unroll
            for (int k = 0; k < 3; ++k) acc = fmaf(Ry[i * 3 + k], Rz[k * 3 + j], acc);
            M[i * 3 + j] = acc;
        }
#pragma unroll
    for (int i = 0; i < 3; ++i)
#pragma unroll
        for (int j = 0; j < 3; ++j) {
            float acc = 0.f;
#pragma unroll
            for (int k = 0; k < 3; ++k) acc = fmaf(Rx[i * 3 + k], M[k * 3 + j], acc);
            Rm[i * 3 + j] = acc;
        }
    const float MINV = -3.602826f;
    float v0 = MINV - o6[n * 6 + 3];
    float v1 = MINV - o6[n * 6 + 4];
    float v2 = MINV - o6[n * 6 + 5];
#pragma unroll
    for (int i = 0; i < 3; ++i) {
        float sh = Rm[i * 3 + 0] * v0 + Rm[i * 3 + 1] * v1 + Rm[i * 3 + 2] * v2;
        bv[n * 3 + i] = 255.f * (sh - MINV) / 8.812765f;
        R[n * 9 + i * 3 + 0] = Rm[i * 3 + 0];
        R[n * 9 + i * 3 + 1] = Rm[i * 3 + 1];
        R[n * 9 + i * 3 + 2] = Rm[i * 3 + 2];
    }
}

// z = R.x + bias -> padded NHWC-C4 bf16 (Hp=226, Wp=232, halo 1)
__global__ void rot_apply5(const float* __restrict__ xc, const float* __restrict__ R,
                           const float* __restrict__ bv, u16* __restrict__ z,
                           int m, int total) {
    int idx = blockIdx.x * blockDim.x + threadIdx.x;
    if (idx >= total) return;
    int n = idx / 50176;
    int p = idx - n * 50176;
    int y = p / 224, xx = p - y * 224;
    float x0 = xc[(((size_t)(n * 3 + 0)) * 50176 + p) * 2 + m];
    float x1 = xc[(((size_t)(n * 3 + 1)) * 50176 + p) * 2 + m];
    float x2 = xc[(((size_t)(n * 3 + 2)) * 50176 + p) * 2 + m];
    u16 o[4];
#pragma unroll
    for (int i = 0; i < 3; ++i) {
        float v = fmaf(R[n * 9 + i * 3 + 0], x0,
                  fmaf(R[n * 9 + i * 3 + 1], x1,
                  fmaf(R[n * 9 + i * 3 + 2], x2, bv[n * 3 + i])));
        o[i] = f2bf(v);
    }
    o[3] = 0;
    size_t ob = (((size_t)n * 226 + y + 1) * 232 + xx + 1) * 4;
    *reinterpret_cast<u16x4*>(&z[ob]) = *reinterpret_cast<u16x4*>(o);
}

// ---------------------------------------------------------------------------
static inline int nblk(size_t total, int bs) { return (int)((total + bs - 1) / bs); }

extern "C" void kernel_launch(void* const* d_in, const int* in_sizes, int n_in,
                              void* d_out, int out_size, void* d_ws, size_t ws_size,
                              hipStream_t stream) {
    const float* x   = (const float*)d_in[0];
    const float* w1  = (const float*)d_in[1];
    const float* b1  = (const float*)d_in[2];
    const float* g1  = (const float*)d_in[3];
    const float* be1 = (const float*)d_in[4];
    const float* w2  = (const float*)d_in[5];
    const float* b2  = (const float*)d_in[6];
    const float* g2  = (const float*)d_in[7];
    const float* be2 = (const float*)d_in[8];
    const float* fw  = (const float*)d_in[9];
    const float* fb  = (const float*)d_in[10];
    const float* bw[5], *bg[5], *bb[5];
    for (int i = 0; i < 5; ++i) {
        bw[i] = (const float*)d_in[11 + 3 * i];
        bg[i] = (const float*)d_in[12 + 3 * i];
        bb[i] = (const float*)d_in[13 + 3 * i];
    }
    const float* lw = (const float*)d_in[26];
    const float* lb = (const float*)d_in[27];
    float* out = (float*)d_out;

    const int N = 32;
    const int BS = 256;
    const size_t S_Pp = 100352;

    const size_t E_X4 = (size_t)228 * 232 * 4;   // also hosts Z16p (226*232*4)
    const size_t E_B1 = (size_t)116 * 116 * 128;
    const size_t E_Zb2 = (size_t)114 * 114 * 64;
    const size_t E_Zb3 = (size_t)58 * 58 * 256;
    const size_t E_Zb4 = (size_t)30 * 30 * 512;
    const size_t E_Zb5 = (size_t)16 * 16 * 1024;

    // SLOTC hosts: C2f (f32), Zb2 (u16), bw4/bw5 split-K partials (f32)
    const size_t slotC_B = E_Zb2 * 2;            // 1,663,488 B/sample
    const size_t per_sample_B = E_X4 * 2 + E_B1 * 2 + slotC_B + S_Pp * 4;
    const size_t apack_u16 = (size_t)128 * 320 + (size_t)128 * 6400 + (size_t)64 * 96 +
                             (size_t)256 * 576 + (size_t)512 * 2304 +
                             (size_t)1024 * 4608 + (size_t)2048 * 9216;
    const size_t fixed_B = (size_t)N * S_Pp * 4 + 131072 * 4 + 8192 + apack_u16 * 2 + 4096;

    int Nc = N;
    while (Nc > 1 && (size_t)Nc * per_sample_B + fixed_B > ws_size) Nc >>= 1;

    // ---- carve workspace ----
    char* cur = (char*)d_ws;
    auto alf = [&](size_t n) { float* p = (float*)cur; cur += ((n + 3) & ~(size_t)3) * 4; return p; };
    auto alu = [&](size_t n) { u16* p = (u16*)cur; cur += ((n + 7) & ~(size_t)7) * 2; return p; };

    float* PM = alf((size_t)N * S_Pp);
    float* O6 = alf(256);
    float* Rm = alf(384);
    float* BV = alf(384);
    float* LP = alf(131072);
    u16* Ap1 = alu((size_t)128 * 320);
    u16* Ap2 = alu((size_t)128 * 6400);
    u16* Ab1 = alu((size_t)64 * 96);
    u16* Ab2 = alu((size_t)256 * 576);
    u16* Ab3 = alu((size_t)512 * 2304);
    u16* Ab4 = alu((size_t)1024 * 4608);
    u16* Ab5 = alu((size_t)2048 * 9216);

    u16* X4p   = alu((size_t)Nc * E_X4);
    u16* Z16p  = X4p;                            // time-disjoint alias
    u16* B1p   = alu((size_t)Nc * E_B1);         // also hosts Zb3/Zb4/Zb5
    u16* Zb3   = B1p;
    u16* Zb4   = Zb3 + (size_t)Nc * E_Zb3;
    u16* Zb5   = Zb4 + (size_t)Nc * E_Zb4;
    u16* SLOTC = alu((size_t)Nc * slotC_B / 2);  // C2f / Zb2 / split-K partials
    float* C2f = (float*)SLOTC;
    u16* Zb2   = SLOTC;
    float* PartF = (float*)SLOTC;
    float* Pp  = alf((size_t)Nc * S_Pp);

    // ---- weight packs ----
    repack_g4_2<<<nblk((size_t)128 * 320, BS), BS, 0, stream>>>(w1, Ap1, 128, 3, 5, 5);
    repack_split2<<<nblk((size_t)128 * 6400, BS), BS, 0, stream>>>(w2, Ap2, 128, 128, 128, 25, 100);
    repack_g4<<<nblk((size_t)64 * 96, BS), BS, 0, stream>>>(bw[0], Ab1, 64, 3, 3, 96);
    repack_w32<<<nblk((size_t)256 * 576, BS), BS, 0, stream>>>(bw[1], Ab2, 256, 64, 9);
    repack_w32<<<nblk((size_t)512 * 2304, BS), BS, 0, stream>>>(bw[2], Ab3, 512, 256, 9);
    repack_w32<<<nblk((size_t)1024 * 4608, BS), BS, 0, stream>>>(bw[3], Ab4, 1024, 512, 9);
    repack_w32<<<nblk((size_t)2048 * 9216, BS), BS, 0, stream>>>(bw[4], Ab5, 2048, 1024, 9);

    zero_u16<<<nblk((size_t)Nc * E_X4 / 8, BS), BS, 0, stream>>>(X4p, (size_t)Nc * E_X4 / 8);

    const int NHW1 = Nc * 12544;
    const int Nb1 = (NHW1 + 127) / 128;
    const int NHW2 = Nc * 3136;
    const int Nb2 = (NHW2 + 127) / 128;
    const int NHW3 = Nc * 784;
    const int Nb3 = (NHW3 + 127) / 128;
    const int NHW4 = Nc * 196;
    const int Nb4 = (NHW4 + 127) / 128;
    const int NHW5 = Nc * 49;
    const int Nb5 = (NHW5 + 127) / 128;
    const size_t str4 = (size_t)NHW4 * 1024;
    const size_t str5 = (size_t)NHW5 * 2048;

    for (int m = 0; m < 2; ++m) {
        for (int c0 = 0; c0 < N; c0 += Nc) {
            const float* xc = x + (size_t)c0 * 150528 * 2;
            int nNP = Nc * 50176;
            // restore X4p halo (scribbled by previous iteration's Z16p use)
            zero_halo_c4<<<nblk((size_t)Nc * 228 * 232, BS), BS, 0, stream>>>(
                X4p, Nc, 228, 232, 2, 224, 224);
            extract_person4<<<nblk(nNP, BS), BS, 0, stream>>>(xc, X4p, m, nNP);

            zero_halo<<<nblk((size_t)Nc * 116 * 116, BS), BS, 0, stream>>>(B1p, Nc, 116, 116, 128, 2, 112, 112);

            // conv1: CT4 gather, 2-set split, BM=128, bf16 out padded NHWC
            gconv<128, 4, true, 0><<<Nb1, 256, 0, stream>>>(
                Ap1, X4p, b1, g1, be1, B1p, nullptr,
                Nb1, NHW1, 5, 1, 4, 228, 232, 5, 112, 12544, 128, 116, 116, 2);
            // conv2: BM=64 (R16 measured win: 268->240us, FETCH 318->199MB)
            gconv<64, 32, true, 2><<<2 * Nb2, 256, 0, stream>>>(
                Ap2, B1p, b2, g2, be2, nullptr, C2f,
                Nb2, NHW2, 100, 1, 128, 116, 116, 5, 56, 3136, 128, 0, 0, 0);
            maxpool2<<<nblk((size_t)Nc * S_Pp, BS), BS, 0, stream>>>(C2f, Pp, Nc * 128, 56, 56);

            lin_part<<<64 * Nc, 256, 0, stream>>>(Pp, fw, LP, 100352, 1568, 6, Nc);
            lin_reduce<<<nblk(Nc * 6, 64), 64, 0, stream>>>(LP, fb, O6, 6, Nc, 64);
            make_rot<<<1, 64, 0, stream>>>(O6, Rm, BV, Nc);
            // Z16p (aliases X4p, conv1 done): zero its halo then write interior
            zero_halo_c4<<<nblk((size_t)Nc * 226 * 232, BS), BS, 0, stream>>>(
                Z16p, Nc, 226, 232, 1, 224, 224);
            rot_apply5<<<nblk(nNP, BS), BS, 0, stream>>>(xc, Rm, BV, Z16p, m, nNP);

            zero_halo<<<nblk((size_t)Nc * 114 * 114, BS), BS, 0, stream>>>(Zb2, Nc, 114, 114, 64, 1, 112, 112);
            zero_halo<<<nblk((size_t)Nc * 58 * 58, BS), BS, 0, stream>>>(Zb3, Nc, 58, 58, 256, 1, 56, 56);
            zero_halo<<<nblk((size_t)Nc * 30 * 30, BS), BS, 0, stream>>>(Zb4, Nc, 30, 30, 512, 1, 28, 28);
            zero_halo<<<nblk((size_t)Nc * 16 * 16, BS), BS, 0, stream>>>(Zb5, Nc, 16, 16, 1024, 1, 14, 14);

            // backbone (R13 tile configs for bw1..bw5)
            gconv<64, 4, false, 0><<<Nb1, 256, 0, stream>>>(
                Ab1, Z16p, nullptr, bg[0], bb[0], Zb2, nullptr,
                Nb1, NHW1, 3, 1, 4, 226, 232, 3, 112, 12544, 64, 114, 114, 1);
            gconv<128, 32, false, 0><<<2 * Nb2, 256, 0, stream>>>(
                Ab2, Zb2, nullptr, bg[1], bb[1], Zb3, nullptr,
                Nb2, NHW2, 18, 1, 64, 114, 114, 3, 56, 3136, 256, 58, 58, 1);
            gconv<128, 32, false, 0><<<4 * Nb3, 256, 0, stream>>>(
                Ab3, Zb3, nullptr, bg[2], bb[2], Zb4, nullptr,
                Nb3, NHW3, 72, 1, 256, 58, 58, 3, 28, 784, 512, 30, 30, 1);
            // bw4: BM=128, split-K=2 -> reduce -> padded NHWC Zb5
            gconv<128, 32, false, 3><<<8 * 2 * Nb4, 256, 0, stream>>>(
                Ab4, Zb4, nullptr, nullptr, nullptr, nullptr, PartF,
                Nb4, NHW4, 144, 2, 512, 30, 30, 3, 14, 196, 1024, 0, 0, 0);
            ksum_nhwc<<<nblk((size_t)NHW4 * 256, BS), BS, 0, stream>>>(
                PartF, bg[3], bb[3], Zb5, NHW4, 196, 14, 1024, 16, 16, 1, 2, str4);
            // bw5: BM=128, split-K=4 -> reduce (+BN+ReLU) -> PMc (max on m=1)
            gconv<128, 32, false, 3><<<16 * 4 * Nb5, 256, 0, stream>>>(
                Ab5, Zb5, nullptr, nullptr, nullptr, nullptr, PartF,
                Nb5, NHW5, 288, 4, 1024, 16, 16, 3, 7, 49, 2048, 0, 0, 0);
            float* PMc = PM + (size_t)c0 * S_Pp;
            ksum_nchw<<<nblk((size_t)NHW5 * 2048, BS), BS, 0, stream>>>(
                PartF, bg[4], bb[4], PMc, (size_t)NHW5 * 2048, str5, 49, 2048, 4, m);
        }
    }

    lin_part<<<64 * N, 256, 0, stream>>>(PM, lw, LP, 100352, 1568, 60, N);
    lin_reduce<<<nblk(N * 60, 64), 64, 0, stream>>>(LP, lb, out, 60, N, 64);
}